// Round 3
// baseline (580.583 us; speedup 1.0000x reference)
//
#include <hip/hip_runtime.h>
#include <hip/hip_bf16.h>

#define B_ 32
#define T_ 4096
#define H_ 512
#define NEGV (-1000000000.0f)

using bf16x8  = __attribute__((ext_vector_type(8))) __bf16;
using short8  = __attribute__((ext_vector_type(8))) short;
using f32x4   = __attribute__((ext_vector_type(4))) float;

static __device__ __forceinline__ short f2bf(float f) {
    unsigned u = __builtin_bit_cast(unsigned, f);
    unsigned r = (u + 0x7fffu + ((u >> 16) & 1u)) >> 16;
    return (short)r;
}

static __device__ __forceinline__ float tanh_fast(float x) {
    float e = __builtin_amdgcn_exp2f(x * 2.8853900817779268f); // 2*log2(e)
    return 1.0f - 2.0f * __builtin_amdgcn_rcpf(e + 1.0f);
}

static __device__ __forceinline__ f32x4 mfma16(short8 a, short8 b, f32x4 c) {
    return __builtin_amdgcn_mfma_f32_16x16x32_bf16(
        __builtin_bit_cast(bf16x8, a), __builtin_bit_cast(bf16x8, b), c, 0, 0, 0);
}

#define GLOAD_LDS16(g, l)                                                     \
    __builtin_amdgcn_global_load_lds(                                         \
        (const __attribute__((address_space(1))) unsigned*)(g),               \
        (__attribute__((address_space(3))) unsigned*)(l), 16, 0, 0)

// ---------------------------------------------------------------------------
// Kernel 0: Wh fp32 -> bf16, 16-row chunks, swizzled 16B slots.
// Row n, 16B-chunk kc: Whp[(n>>4)*8192 + (n&15)*512 + ((kc^(n&7))<<3)]
__global__ __launch_bounds__(256) void wh_prep(const float* __restrict__ Wh,
                                               short* __restrict__ Whp) {
    int id = blockIdx.x * 256 + threadIdx.x;   // 32768 = 512 rows x 64 chunks
    int n = id >> 6, kc = id & 63;
    const float4* src = (const float4*)(Wh + (size_t)n * H_ + kc * 8);
    float4 f0 = src[0];
    float4 f1 = src[1];
    short8 t;
    t[0] = f2bf(f0.x); t[1] = f2bf(f0.y); t[2] = f2bf(f0.z); t[3] = f2bf(f0.w);
    t[4] = f2bf(f1.x); t[5] = f2bf(f1.y); t[6] = f2bf(f1.z); t[7] = f2bf(f1.w);
    *(short8*)(Whp + (n >> 4) * 8192 + (n & 15) * 512 + ((kc ^ (n & 7)) << 3)) = t;
}

// ---------------------------------------------------------------------------
// Kernel 1: s[b,o] = sum_k dec[b,k] * Ws[o,k]
__global__ __launch_bounds__(256) void s_kernel(const float* __restrict__ dec,
                                                const float* __restrict__ Ws,
                                                float* __restrict__ s_out) {
    __shared__ float dec_l[H_];
    int b = blockIdx.y;
    int tid = threadIdx.x;
    dec_l[tid]       = dec[b * H_ + tid];
    dec_l[tid + 256] = dec[b * H_ + tid + 256];
    __syncthreads();
    int o = blockIdx.x * 256 + tid;
    const float4* w = (const float4*)(Ws + (size_t)o * H_);
    float acc = 0.f;
#pragma unroll 8
    for (int k = 0; k < H_ / 4; ++k) {
        float4 wv = w[k];
        acc += wv.x * dec_l[4 * k] + wv.y * dec_l[4 * k + 1] +
               wv.z * dec_l[4 * k + 2] + wv.w * dec_l[4 * k + 3];
    }
    s_out[b * H_ + o] = acc;
}

// ---------------------------------------------------------------------------
// Kernel 2: e[b,t] = v . tanh(enc[b,t,:] @ Wh^T + s[b,:]), masked.
// 16-row N-chunks, double-buffered (2x16 KiB), one barrier per chunk,
// A-frags resident in VGPRs, __launch_bounds__(256,3) -> 3 blocks/CU.
__global__ __launch_bounds__(256, 3) void e_kernel(const float* __restrict__ enc,
                                                   const int* __restrict__ mask,
                                                   const short* __restrict__ Whp,
                                                   const float* __restrict__ s_in,
                                                   const float* __restrict__ v,
                                                   float* __restrict__ e_out) {
    __shared__ short lds_b[2][16 * 512];   // 2 x 16 KiB
    __shared__ float2 sv_l[H_];            // {s, v}

    const int tid  = threadIdx.x;
    const int wave = tid >> 6;
    const int lane = tid & 63;
    const int q    = lane >> 4;
    const int lq   = lane & 15;
    const int key  = lq & 7;

    const int row0 = blockIdx.x * 128;
    const int b    = row0 / T_;

    for (int i = tid; i < H_; i += 256)
        sv_l[i] = make_float2(s_in[b * H_ + i], v[i]);

    // A rows (32 per wave x 512 K) as bf16 fragments in registers.
    short8 afrag[2][16];
#pragma unroll
    for (int g = 0; g < 2; ++g) {
        int m = row0 + wave * 32 + g * 16 + lq;
        const float* ap = enc + (size_t)m * H_ + q * 8;
#pragma unroll
        for (int ks = 0; ks < 16; ++ks) {
            float4 f0 = *(const float4*)(ap + ks * 32);
            float4 f1 = *(const float4*)(ap + ks * 32 + 4);
            short8 t;
            t[0] = f2bf(f0.x); t[1] = f2bf(f0.y); t[2] = f2bf(f0.z); t[3] = f2bf(f0.w);
            t[4] = f2bf(f1.x); t[5] = f2bf(f1.y); t[6] = f2bf(f1.z); t[7] = f2bf(f1.w);
            afrag[g][ks] = t;
        }
    }

    // Prefetch chunk 0: 16 KiB = 4 waves x 4 x 1 KiB.
#pragma unroll
    for (int j = 0; j < 4; ++j) {
        int off = wave * 4096 + j * 1024;
        GLOAD_LDS16((const char*)Whp + off + lane * 16, (char*)lds_b[0] + off);
    }

    float e_acc[2][4] = {};
    __syncthreads();

    for (int nt = 0; nt < 32; ++nt) {
        if (nt < 31) {
            const char* gsrc = (const char*)Whp + (nt + 1) * 16384;
            char* dst = (char*)lds_b[(nt + 1) & 1];
#pragma unroll
            for (int j = 0; j < 4; ++j) {
                int off = wave * 4096 + j * 1024;
                GLOAD_LDS16(gsrc + off + lane * 16, dst + off);
            }
        }
        const short* rowp = lds_b[nt & 1] + lq * 512;
        f32x4 acc0 = {0.f, 0.f, 0.f, 0.f};
        f32x4 acc1 = {0.f, 0.f, 0.f, 0.f};
#pragma unroll
        for (int ks = 0; ks < 16; ++ks) {
            short8 bf = *(const short8*)(rowp + (((ks * 4 + q) ^ key) << 3));
            acc0 = mfma16(afrag[0][ks], bf, acc0);
            acc1 = mfma16(afrag[1][ks], bf, acc1);
        }
        float2 sv = sv_l[nt * 16 + lq];
#pragma unroll
        for (int r = 0; r < 4; ++r) {
            e_acc[0][r] += tanh_fast(acc0[r] + sv.x) * sv.y;
            e_acc[1][r] += tanh_fast(acc1[r] + sv.x) * sv.y;
        }
        __syncthreads();
    }

#pragma unroll
    for (int g = 0; g < 2; ++g)
#pragma unroll
        for (int r = 0; r < 4; ++r) {
            float t = e_acc[g][r];
            t += __shfl_xor(t, 1, 16);
            t += __shfl_xor(t, 2, 16);
            t += __shfl_xor(t, 4, 16);
            t += __shfl_xor(t, 8, 16);
            if (lq == 0) {
                int m = row0 + wave * 32 + g * 16 + q * 4 + r;
                e_out[m] = mask[m] ? t : NEGV;
            }
        }
}

// ---------------------------------------------------------------------------
// Kernel 3: in-place softmax over T per batch. grid (B), block 1024.
__global__ __launch_bounds__(1024) void softmax_kernel(float* __restrict__ e) {
    __shared__ float red[16];
    int b = blockIdx.x, tid = threadIdx.x;
    int wid = tid >> 6, lane = tid & 63;
    float* eb = e + (size_t)b * T_;
    float4 x = *(float4*)(eb + tid * 4);

    float m = fmaxf(fmaxf(x.x, x.y), fmaxf(x.z, x.w));
#pragma unroll
    for (int s = 1; s < 64; s <<= 1) m = fmaxf(m, __shfl_xor(m, s, 64));
    if (lane == 0) red[wid] = m;
    __syncthreads();
    m = red[0];
#pragma unroll
    for (int j = 1; j < 16; ++j) m = fmaxf(m, red[j]);
    __syncthreads();

    const float L2E = 1.4426950408889634f;
    x.x = __builtin_amdgcn_exp2f((x.x - m) * L2E);
    x.y = __builtin_amdgcn_exp2f((x.y - m) * L2E);
    x.z = __builtin_amdgcn_exp2f((x.z - m) * L2E);
    x.w = __builtin_amdgcn_exp2f((x.w - m) * L2E);
    float sum = x.x + x.y + x.z + x.w;
#pragma unroll
    for (int s = 1; s < 64; s <<= 1) sum += __shfl_xor(sum, s, 64);
    if (lane == 0) red[wid] = sum;
    __syncthreads();
    sum = 0.f;
#pragma unroll
    for (int j = 0; j < 16; ++j) sum += red[j];

    float inv = 1.0f / sum;
    x.x *= inv; x.y *= inv; x.z *= inv; x.w *= inv;
    *(float4*)(eb + tid * 4) = x;
}

// ---------------------------------------------------------------------------
// Kernel 4a: partial ctx. grid (T/256, B), block 256.
// thread = (h-quad tid&127, t-parity tid>>7); float4 loads; no atomics.
__global__ __launch_bounds__(256) void ctx_stage1(const float* __restrict__ enc,
                                                  const float* __restrict__ a,
                                                  float* __restrict__ part) {
    constexpr int TC = 256;
    __shared__ float a_l[TC];
    int b = blockIdx.y, tc = blockIdx.x;
    int tid = threadIdx.x;
    int t0 = tc * TC;
    a_l[tid] = a[(size_t)b * T_ + t0 + tid];
    __syncthreads();
    int hq = tid & 127, tpar = tid >> 7;
    const float4* ep = (const float4*)(enc + ((size_t)b * T_ + t0) * H_) + hq;
    float4 acc = {0.f, 0.f, 0.f, 0.f};
#pragma unroll 8
    for (int t = tpar; t < TC; t += 2) {
        float4 v4 = ep[(size_t)t * (H_ / 4)];
        float w = a_l[t];
        acc.x += w * v4.x; acc.y += w * v4.y;
        acc.z += w * v4.z; acc.w += w * v4.w;
    }
    float4* pp = (float4*)(part + ((size_t)(b * 32 + tc * 2 + tpar)) * H_) + hq;
    *pp = acc;
}

// Kernel 4b: reduce 32 partials. grid (B), block 512.
__global__ __launch_bounds__(512) void ctx_stage2(const float* __restrict__ part,
                                                  float* __restrict__ out) {
    int b = blockIdx.x, h = threadIdx.x;
    const float* p = part + (size_t)b * 32 * H_ + h;
    float acc = 0.f;
#pragma unroll
    for (int j = 0; j < 32; ++j) acc += p[j * H_];
    out[b * H_ + h] = acc;
}

// ---------------------------------------------------------------------------
extern "C" void kernel_launch(void* const* d_in, const int* in_sizes, int n_in,
                              void* d_out, int out_size, void* d_ws, size_t ws_size,
                              hipStream_t stream) {
    (void)in_sizes; (void)n_in; (void)ws_size; (void)out_size;
    const float* enc  = (const float*)d_in[0];
    const int*   mask = (const int*)d_in[1];
    const float* dec  = (const float*)d_in[2];
    const float* Wh   = (const float*)d_in[3];
    const float* Ws   = (const float*)d_in[4];
    const float* v    = (const float*)d_in[5];
    float* out = (float*)d_out;

    short* whp_buf = (short*)d_ws;                        // 512 KiB
    float* s_buf   = (float*)(whp_buf + 512 * 512);       // 64 KiB
    float* e_buf   = s_buf + B_ * H_;                     // 512 KiB
    float* part    = e_buf + B_ * T_;                     // 2 MiB

    wh_prep<<<dim3(128), 256, 0, stream>>>(Wh, whp_buf);
    s_kernel<<<dim3(2, B_), 256, 0, stream>>>(dec, Ws, s_buf);
    e_kernel<<<dim3(B_ * T_ / 128), 256, 0, stream>>>(enc, mask, whp_buf, s_buf, v, e_buf);
    softmax_kernel<<<dim3(B_), 1024, 0, stream>>>(e_buf);
    ctx_stage1<<<dim3(T_ / 256, B_), 256, 0, stream>>>(enc, e_buf, part);
    ctx_stage2<<<dim3(B_), 512, 0, stream>>>(part, out);
}